// Round 8
// baseline (598.430 us; speedup 1.0000x reference)
//
#include <hip/hip_runtime.h>
#include <math.h>

typedef __attribute__((ext_vector_type(8))) short short8;
typedef __attribute__((ext_vector_type(4))) float f32x4;

#define HID 170
#define PLANE 65536

__device__ __forceinline__ unsigned short f2bf(float f) {
  unsigned u = __float_as_uint(f);
  u += 0x7FFFu + ((u >> 16) & 1u);
  return (unsigned short)(u >> 16);
}
__device__ __forceinline__ float bf2f(unsigned short h) {
  return __uint_as_float(((unsigned)h) << 16);
}
__device__ __forceinline__ float bf2f_lo(unsigned v) { return __uint_as_float(v << 16); }
__device__ __forceinline__ float bf2f_hi(unsigned v) { return __uint_as_float(v & 0xFFFF0000u); }
__device__ __forceinline__ unsigned pack2bf(float a, float b) {
  return (unsigned)f2bf(a) | ((unsigned)f2bf(b) << 16);
}
__device__ __forceinline__ f32x4 mfma16(short8 a, short8 b, f32x4 c) {
  return __builtin_amdgcn_mfma_f32_16x16x32_bf16(a, b, c, 0, 0, 0);
}
__device__ __forceinline__ uint2 pack4bf(f32x4 v) {
  uint2 r;
  r.x = pack2bf(v[0], v[1]);
  r.y = pack2bf(v[2], v[3]);
  return r;
}

// ============ prepack ======================================================
__global__ void prepack_kernel(const float* __restrict__ qkv_w, const float* __restrict__ proj_w,
                               const float* __restrict__ pin_w, const float* __restrict__ pout_w,
                               short* __restrict__ pq, short* __restrict__ pp,
                               short* __restrict__ pi, short* __restrict__ po) {
  int idx = blockIdx.x * 256 + threadIdx.x;
  if (idx < 12288) {  // qkv: 12 mt x 2 ks
    int j = idx & 7, ln = (idx >> 3) & 63, ks = (idx >> 9) & 1, mt = idx >> 10;
    int row = mt * 16 + (ln & 15), k = ks * 32 + (ln >> 4) * 8 + j;
    pq[idx] = (short)f2bf(qkv_w[row * 64 + k]);
  }
  if (idx < 4096) {   // proj: 4 x 2
    int j = idx & 7, ln = (idx >> 3) & 63, ks = (idx >> 9) & 1, mt = idx >> 10;
    int row = mt * 16 + (ln & 15), k = ks * 32 + (ln >> 4) * 8 + j;
    pp[idx] = (short)f2bf(proj_w[row * 64 + k]);
  }
  if (idx < 22528) {  // pin: 22 mt x 2 ks, PAIR-INTERLEAVED rows (y_i, z_i)
    int j = idx & 7, ln = (idx >> 3) & 63, ks = (idx >> 9) & 1, mt = idx >> 10;
    int r = mt * 16 + (ln & 15);       // 0..351
    int k = ks * 32 + (ln >> 4) * 8 + j;
    int i = r >> 1, half = r & 1;
    float v = 0.f;
    if (i < HID) v = pin_w[(half ? HID + i : i) * 64 + k];
    pi[idx] = (short)f2bf(v);
  }
  if (idx < 12288) {  // pout: 4 mt x 6 ks (K = gate idx, padded 170->192)
    int j = idx & 7, ln = (idx >> 3) & 63, ks = (idx >> 9) % 6, mt = idx / 3072;
    int o = mt * 16 + (ln & 15), k = ks * 32 + (ln >> 4) * 8 + j;
    float v = (k < HID) ? pout_w[o * HID + k] : 0.f;
    po[idx] = (short)f2bf(v);
  }
}

// ============ gemm_qkv: LN1 + qkv 1x1 conv (per 64-pos tile) ===============
// writes y1 [pos][192] bf16 (quarter-local)
__global__ __launch_bounds__(256) void gemm_qkv(
    const float* __restrict__ src, const float* __restrict__ lnw,
    const float* __restrict__ lnb, const short* __restrict__ pq,
    unsigned short* __restrict__ y1) {
  __shared__ __align__(16) char smem[24832];
  short* xn = (short*)smem;            // 8192
  float* xT = (float*)(smem + 8192);   // 64x65 f32 = 16640
  const int t = threadIdx.x;
  const int posbase = blockIdx.x << 6;
  {
    int c = t >> 2, q = t & 3;
    const float* sp = src + ((size_t)c << 16) + posbase + q * 16;
    float4 v0 = *(const float4*)(sp);
    float4 v1 = *(const float4*)(sp + 4);
    float4 v2 = *(const float4*)(sp + 8);
    float4 v3 = *(const float4*)(sp + 12);
    float* row = xT + c * 65 + q * 16;
    row[0]=v0.x; row[1]=v0.y; row[2]=v0.z; row[3]=v0.w;
    row[4]=v1.x; row[5]=v1.y; row[6]=v1.z; row[7]=v1.w;
    row[8]=v2.x; row[9]=v2.y; row[10]=v2.z; row[11]=v2.w;
    row[12]=v3.x; row[13]=v3.y; row[14]=v3.z; row[15]=v3.w;
  }
  __syncthreads();
  {
    int p = t >> 2, q = t & 3;
    float s = 0.f, s2 = 0.f;
    float vv[16];
#pragma unroll
    for (int i = 0; i < 16; ++i) {
      float v = xT[(q * 16 + i) * 65 + p];
      vv[i] = v; s += v; s2 += v * v;
    }
    s += __shfl_xor(s, 1); s2 += __shfl_xor(s2, 1);
    s += __shfl_xor(s, 2); s2 += __shfl_xor(s2, 2);
    float mu = s * (1.f / 64.f);
    float var = s2 * (1.f / 64.f) - mu * mu;
    float rstd = rsqrtf(var + 1e-5f);
    short8 o0, o1;
#pragma unroll
    for (int i = 0; i < 8; ++i) {
      o0[i] = (short)f2bf((vv[i] - mu) * rstd * lnw[q * 16 + i] + lnb[q * 16 + i]);
      o1[i] = (short)f2bf((vv[8 + i] - mu) * rstd * lnw[q * 16 + 8 + i] + lnb[q * 16 + 8 + i]);
    }
    *(short8*)(xn + p * 64 + (((2 * q) ^ (p & 7)) << 3)) = o0;
    *(short8*)(xn + p * 64 + (((2 * q + 1) ^ (p & 7)) << 3)) = o1;
  }
  __syncthreads();
  const int lane = t & 63, wid = t >> 6;
  const int l15 = lane & 15, q4 = lane >> 4;
#pragma unroll
  for (int m = 0; m < 3; ++m) {
    int mt = wid * 3 + m;
    short8 a0 = *(const short8*)(pq + ((mt * 2 + 0) * 64 + lane) * 8);
    short8 a1 = *(const short8*)(pq + ((mt * 2 + 1) * 64 + lane) * 8);
#pragma unroll
    for (int nt = 0; nt < 4; ++nt) {
      int pos = nt * 16 + l15;
      short8 b0 = *(const short8*)(xn + pos * 64 + (((q4) ^ (pos & 7)) << 3));
      short8 b1 = *(const short8*)(xn + pos * 64 + (((4 + q4) ^ (pos & 7)) << 3));
      f32x4 acc = {0.f, 0.f, 0.f, 0.f};
      acc = mfma16(a0, b0, acc);
      acc = mfma16(a1, b1, acc);
      *(uint2*)(y1 + (size_t)(posbase + pos) * 192 + mt * 16 + q4 * 4) = pack4bf(acc);
    }
  }
}

// ============ gemm_pin: LN2 + pin 1x1 conv =================================
// writes y2 [pos][352] bf16 pair-interleaved (cols 340..351 zero)
__global__ __launch_bounds__(256) void gemm_pin(
    const float* __restrict__ src, const float* __restrict__ lnw,
    const float* __restrict__ lnb, const short* __restrict__ pi,
    unsigned short* __restrict__ y2) {
  __shared__ __align__(16) char smem[24832];
  short* xn = (short*)smem;
  float* xT = (float*)(smem + 8192);
  const int t = threadIdx.x;
  const int posbase = blockIdx.x << 6;
  {
    int c = t >> 2, q = t & 3;
    const float* sp = src + ((size_t)c << 16) + posbase + q * 16;
    float4 v0 = *(const float4*)(sp);
    float4 v1 = *(const float4*)(sp + 4);
    float4 v2 = *(const float4*)(sp + 8);
    float4 v3 = *(const float4*)(sp + 12);
    float* row = xT + c * 65 + q * 16;
    row[0]=v0.x; row[1]=v0.y; row[2]=v0.z; row[3]=v0.w;
    row[4]=v1.x; row[5]=v1.y; row[6]=v1.z; row[7]=v1.w;
    row[8]=v2.x; row[9]=v2.y; row[10]=v2.z; row[11]=v2.w;
    row[12]=v3.x; row[13]=v3.y; row[14]=v3.z; row[15]=v3.w;
  }
  __syncthreads();
  {
    int p = t >> 2, q = t & 3;
    float s = 0.f, s2 = 0.f;
    float vv[16];
#pragma unroll
    for (int i = 0; i < 16; ++i) {
      float v = xT[(q * 16 + i) * 65 + p];
      vv[i] = v; s += v; s2 += v * v;
    }
    s += __shfl_xor(s, 1); s2 += __shfl_xor(s2, 1);
    s += __shfl_xor(s, 2); s2 += __shfl_xor(s2, 2);
    float mu = s * (1.f / 64.f);
    float var = s2 * (1.f / 64.f) - mu * mu;
    float rstd = rsqrtf(var + 1e-5f);
    short8 o0, o1;
#pragma unroll
    for (int i = 0; i < 8; ++i) {
      o0[i] = (short)f2bf((vv[i] - mu) * rstd * lnw[q * 16 + i] + lnb[q * 16 + i]);
      o1[i] = (short)f2bf((vv[8 + i] - mu) * rstd * lnw[q * 16 + 8 + i] + lnb[q * 16 + 8 + i]);
    }
    *(short8*)(xn + p * 64 + (((2 * q) ^ (p & 7)) << 3)) = o0;
    *(short8*)(xn + p * 64 + (((2 * q + 1) ^ (p & 7)) << 3)) = o1;
  }
  __syncthreads();
  const int lane = t & 63, wid = t >> 6;
  const int l15 = lane & 15, q4 = lane >> 4;
#pragma unroll
  for (int m = 0; m < 6; ++m) {
    int mt = m * 4 + wid;
    if (mt < 22) {
      short8 a0 = *(const short8*)(pi + ((mt * 2 + 0) * 64 + lane) * 8);
      short8 a1 = *(const short8*)(pi + ((mt * 2 + 1) * 64 + lane) * 8);
#pragma unroll
      for (int nt = 0; nt < 4; ++nt) {
        int pos = nt * 16 + l15;
        short8 b0 = *(const short8*)(xn + pos * 64 + (((q4) ^ (pos & 7)) << 3));
        short8 b1 = *(const short8*)(xn + pos * 64 + (((4 + q4) ^ (pos & 7)) << 3));
        f32x4 acc = {0.f, 0.f, 0.f, 0.f};
        acc = mfma16(a0, b0, acc);
        acc = mfma16(a1, b1, acc);
        *(uint2*)(y2 + (size_t)(posbase + pos) * 352 + mt * 16 + q4 * 4) = pack4bf(acc);
      }
    }
  }
}

// ============ attn2: dwconv + channel-attention + proj + residual ==========
#define A2_QKVT 0        // 48 pairs x 102 dw = 19584 (pP/pB overlay after)
#define A2_QK   19584    // 128 x 72 sh = 18432 (ow overlays after P5)
#define A2_VT   38016    // 64 x 72 sh = 9216
#define A2_SCL  47232    // 128 f32 = 512
#define A2_PP   0        // 64 x 33 f32 = 8448
#define A2_PB   8448     // 64 x 40 sh = 5120
#define A2_OW   19584    // 64 x 72 sh = 9216
#define A2_TOT  47744

__global__ __launch_bounds__(512) void attn2_kernel(
    const unsigned short* __restrict__ y1, const float* __restrict__ x,
    const float* __restrict__ qkv_dw, const float* __restrict__ temp,
    const float* __restrict__ proj_b, const short* __restrict__ pk_proj,
    float* __restrict__ x1out) {
  __shared__ __align__(16) char smem[A2_TOT];
  unsigned* qkvt = (unsigned*)(smem + A2_QKVT);
  short* qk  = (short*)(smem + A2_QK);
  short* vt  = (short*)(smem + A2_VT);
  float* scl = (float*)(smem + A2_SCL);
  float* pP  = (float*)(smem + A2_PP);
  short* pB  = (short*)(smem + A2_PB);
  short* ow  = (short*)(smem + A2_OW);
  const unsigned* y1d = (const unsigned*)y1;

  const int tid = threadIdx.x;
  const int lane = tid & 63;
  const int wid = tid >> 6;
  const int l15 = lane & 15, q4 = lane >> 4;
  const int blk = blockIdx.x;
  const int wy = blk >> 5, wx = blk & 31;
  const int gy0 = wy * 8 - 1, gx0 = wx * 8 - 1;

  for (int cc = 0; cc < 2; ++cc) {
    // halo load (transposed into [pair][102] dwords)
    for (int u = tid; u < 4800; u += 512) {
      int p = u / 48, pr = u % 48;
      int py = p / 10, px = p - py * 10;
      int gy = gy0 + py, gx = gx0 + px;
      unsigned v = 0;
      if ((unsigned)gy < 256u && (unsigned)gx < 256u)
        v = y1d[(size_t)(gy * 256 + gx) * 96 + cc * 48 + pr];
      qkvt[pr * 102 + p] = v;
    }
    __syncthreads();
    // dwconv: 48 pairs x 8 rows
    if (tid < 384) {
      int p = tid >> 3, r = tid & 7;
      int gp = cc * 48 + p;
      const float* w0 = qkv_dw + gp * 18;
      const float* w1 = w0 + 9;
      const unsigned* src = qkvt + p * 102;
      float accA[8], accB[8];
#pragma unroll
      for (int j = 0; j < 8; ++j) { accA[j] = 0.f; accB[j] = 0.f; }
#pragma unroll
      for (int t = 0; t < 3; ++t) {
        const unsigned* rp = src + (r + t) * 10;
        uint2 u0 = *(const uint2*)(rp);
        uint2 u1 = *(const uint2*)(rp + 2);
        uint2 u2 = *(const uint2*)(rp + 4);
        uint2 u3 = *(const uint2*)(rp + 6);
        uint2 u4 = *(const uint2*)(rp + 8);
        float lo[10], hi[10];
        lo[0]=bf2f_lo(u0.x); hi[0]=bf2f_hi(u0.x);
        lo[1]=bf2f_lo(u0.y); hi[1]=bf2f_hi(u0.y);
        lo[2]=bf2f_lo(u1.x); hi[2]=bf2f_hi(u1.x);
        lo[3]=bf2f_lo(u1.y); hi[3]=bf2f_hi(u1.y);
        lo[4]=bf2f_lo(u2.x); hi[4]=bf2f_hi(u2.x);
        lo[5]=bf2f_lo(u2.y); hi[5]=bf2f_hi(u2.y);
        lo[6]=bf2f_lo(u3.x); hi[6]=bf2f_hi(u3.x);
        lo[7]=bf2f_lo(u3.y); hi[7]=bf2f_hi(u3.y);
        lo[8]=bf2f_lo(u4.x); hi[8]=bf2f_hi(u4.x);
        lo[9]=bf2f_lo(u4.y); hi[9]=bf2f_hi(u4.y);
        float wa0=w0[t*3], wa1=w0[t*3+1], wa2=w0[t*3+2];
        float wb0=w1[t*3], wb1=w1[t*3+1], wb2=w1[t*3+2];
#pragma unroll
        for (int px = 0; px < 8; ++px) {
          accA[px] = fmaf(wa0, lo[px], fmaf(wa1, lo[px+1], fmaf(wa2, lo[px+2], accA[px])));
          accB[px] = fmaf(wb0, hi[px], fmaf(wb1, hi[px+1], fmaf(wb2, hi[px+2], accB[px])));
        }
      }
      if (gp < 64) {
        short8 sa, sb;
#pragma unroll
        for (int j = 0; j < 8; ++j) { sa[j]=(short)f2bf(accA[j]); sb[j]=(short)f2bf(accB[j]); }
        *(short8*)(qk + (2 * gp) * 72 + r * 8) = sa;
        *(short8*)(qk + (2 * gp + 1) * 72 + r * 8) = sb;
      } else {
        int vb = (gp - 64) * 2;
#pragma unroll
        for (int px = 0; px < 8; ++px)
          *(unsigned*)(vt + (r * 8 + px) * 72 + vb) = pack2bf(accA[px], accB[px]);
      }
    }
    __syncthreads();
  }

  // P4: inverse L2 norms
  {
    int row = tid >> 2, qq = tid & 3;
    const short* r = qk + row * 72 + qq * 16;
    short8 v0 = *(const short8*)(r);
    short8 v1 = *(const short8*)(r + 8);
    float s = 0.f;
#pragma unroll
    for (int j = 0; j < 8; ++j) {
      float f0 = bf2f((unsigned short)v0[j]); s = fmaf(f0, f0, s);
      float f1 = bf2f((unsigned short)v1[j]); s = fmaf(f1, f1, s);
    }
    s += __shfl_xor(s, 1);
    s += __shfl_xor(s, 2);
    if (qq == 0) scl[row] = 1.f / fmaxf(sqrtf(s), 1e-12f);
  }
  __syncthreads();

  // P5: QK^T
  {
    int h = wid >> 2, mt = (wid >> 1) & 1, nt = wid & 1;
    int arow = h * 32 + mt * 16;
    int brow = 64 + h * 32 + nt * 16;
    f32x4 acc = {0.f, 0.f, 0.f, 0.f};
#pragma unroll
    for (int ks = 0; ks < 2; ++ks) {
      short8 a = *(const short8*)(qk + (arow + l15) * 72 + ks * 32 + q4 * 8);
      short8 bb = *(const short8*)(qk + (brow + l15) * 72 + ks * 32 + q4 * 8);
      acc = mfma16(a, bb, acc);
    }
    float tf = temp[h];
    int e = nt * 16 + l15;
    float se = scl[64 + h * 32 + e] * tf;
    int cqb = h * 32 + mt * 16 + q4 * 4;
#pragma unroll
    for (int j = 0; j < 4; ++j)
      pP[(cqb + j) * 33 + e] = acc[j] * scl[cqb + j] * se;
  }
  __syncthreads();

  // P6: softmax
  {
    int row = tid >> 3, l = tid & 7;
    const float* rp = pP + row * 33 + l * 4;
    float e0 = rp[0], e1 = rp[1], e2 = rp[2], e3 = rp[3];
    float m = fmaxf(fmaxf(e0, e1), fmaxf(e2, e3));
    m = fmaxf(m, __shfl_xor(m, 1));
    m = fmaxf(m, __shfl_xor(m, 2));
    m = fmaxf(m, __shfl_xor(m, 4));
    float x0 = __expf(e0 - m), x1v = __expf(e1 - m);
    float x2 = __expf(e2 - m), x3 = __expf(e3 - m);
    float s = x0 + x1v + x2 + x3;
    s += __shfl_xor(s, 1);
    s += __shfl_xor(s, 2);
    s += __shfl_xor(s, 4);
    float inv = 1.f / s;
    unsigned* dp = (unsigned*)(pB + row * 40 + l * 4);
    dp[0] = pack2bf(x0 * inv, x1v * inv);
    dp[1] = pack2bf(x2 * inv, x3 * inv);
  }
  __syncthreads();

  // P7: PV
#pragma unroll
  for (int r = 0; r < 2; ++r) {
    int f = wid + r * 8;
    int h = f >> 3, mt = (f >> 2) & 1, nt = f & 3;
    short8 a = *(const short8*)(pB + (h * 32 + mt * 16 + l15) * 40 + q4 * 8);
    short8 bb = *(const short8*)(vt + (nt * 16 + l15) * 72 + h * 32 + q4 * 8);
    f32x4 acc = {0.f, 0.f, 0.f, 0.f};
    acc = mfma16(a, bb, acc);
    int d = nt * 16 + l15;
    int chb = h * 32 + mt * 16 + q4 * 4;
    unsigned* dp = (unsigned*)(ow + d * 72 + chb);
    dp[0] = pack2bf(acc[0], acc[1]);
    dp[1] = pack2bf(acc[2], acc[3]);
  }
  __syncthreads();

  // P8: proj + bias + residual -> x1
#pragma unroll
  for (int r = 0; r < 2; ++r) {
    int f = wid + r * 8;
    int mt = f >> 2, nt = f & 3;
    f32x4 acc = {0.f, 0.f, 0.f, 0.f};
#pragma unroll
    for (int ks = 0; ks < 2; ++ks) {
      short8 a = *(const short8*)(pk_proj + ((mt * 2 + ks) * 64 + lane) * 8);
      short8 bb = *(const short8*)(ow + (nt * 16 + l15) * 72 + ks * 32 + q4 * 8);
      acc = mfma16(a, bb, acc);
    }
    int pos = nt * 16 + l15;
    int gy = wy * 8 + (pos >> 3), gx = wx * 8 + (pos & 7);
    int ob = mt * 16 + q4 * 4;
#pragma unroll
    for (int j = 0; j < 4; ++j) {
      int o = ob + j;
      size_t gp = (size_t)o * PLANE + gy * 256 + gx;
      x1out[gp] = acc[j] + proj_b[o] + x[gp];
    }
  }
}

// ============ ffn2: dwconv + gelu-gate + pout + residual ===================
#define F2_Y12 0       // 64 pairs x 102 dw = 26112
#define F2_G   26112   // 64 x 200 sh = 25600
#define F2_TOT 51712

__global__ __launch_bounds__(512) void ffn2_kernel(
    const unsigned short* __restrict__ y2,
    const float* __restrict__ dw_w, const short* __restrict__ pk_pout,
    float* __restrict__ out) {
  __shared__ __align__(16) char smem[F2_TOT];
  unsigned* y12 = (unsigned*)(smem + F2_Y12);
  short* g      = (short*)(smem + F2_G);
  const unsigned* y2d = (const unsigned*)y2;

  const int tid = threadIdx.x;
  const int lane = tid & 63;
  const int wid = tid >> 6;
  const int l15 = lane & 15, q4 = lane >> 4;
  const int blk = blockIdx.x;
  const int wy = blk >> 5, wx = blk & 31;
  const int gy0 = wy * 8 - 1, gx0 = wx * 8 - 1;

  // zero g pad cols 170..191 (dwords 85..95 of each row)
  for (int u = tid; u < 704; u += 512) {
    int pos = u / 11, k = u - pos * 11;
    ((unsigned*)g)[pos * 100 + 85 + k] = 0;
  }

  for (int c = 0; c < 3; ++c) {
    // halo load chunk (transposed into [pair][102] dwords)
    for (int u = tid; u < 6400; u += 512) {
      int p = u >> 6, pr = u & 63;
      int py = p / 10, px = p - py * 10;
      int gy = gy0 + py, gx = gx0 + px;
      int gpair = c * 64 + pr;
      unsigned v = 0;
      if ((unsigned)gy < 256u && (unsigned)gx < 256u && gpair < 176)
        v = y2d[(size_t)(gy * 256 + gx) * 176 + gpair];
      y12[pr * 102 + p] = v;
    }
    __syncthreads();
    // dwconv + gelu gate
    {
      int nv = (c < 2) ? 64 : 42;
      int p = tid >> 3, r = tid & 7;
      if (p < nv) {
        int gp = c * 64 + p;
        const float* wY = dw_w + gp * 9;
        const float* wZ = dw_w + (HID + gp) * 9;
        const unsigned* src = y12 + p * 102;
        float accA[8], accB[8];
#pragma unroll
        for (int j = 0; j < 8; ++j) { accA[j] = 0.f; accB[j] = 0.f; }
#pragma unroll
        for (int t = 0; t < 3; ++t) {
          const unsigned* rp = src + (r + t) * 10;
          uint2 u0 = *(const uint2*)(rp);
          uint2 u1 = *(const uint2*)(rp + 2);
          uint2 u2 = *(const uint2*)(rp + 4);
          uint2 u3 = *(const uint2*)(rp + 6);
          uint2 u4 = *(const uint2*)(rp + 8);
          float lo[10], hi[10];
          lo[0]=bf2f_lo(u0.x); hi[0]=bf2f_hi(u0.x);
          lo[1]=bf2f_lo(u0.y); hi[1]=bf2f_hi(u0.y);
          lo[2]=bf2f_lo(u1.x); hi[2]=bf2f_hi(u1.x);
          lo[3]=bf2f_lo(u1.y); hi[3]=bf2f_hi(u1.y);
          lo[4]=bf2f_lo(u2.x); hi[4]=bf2f_hi(u2.x);
          lo[5]=bf2f_lo(u2.y); hi[5]=bf2f_hi(u2.y);
          lo[6]=bf2f_lo(u3.x); hi[6]=bf2f_hi(u3.x);
          lo[7]=bf2f_lo(u3.y); hi[7]=bf2f_hi(u3.y);
          lo[8]=bf2f_lo(u4.x); hi[8]=bf2f_hi(u4.x);
          lo[9]=bf2f_lo(u4.y); hi[9]=bf2f_hi(u4.y);
          float wa0=wY[t*3], wa1=wY[t*3+1], wa2=wY[t*3+2];
          float wb0=wZ[t*3], wb1=wZ[t*3+1], wb2=wZ[t*3+2];
#pragma unroll
          for (int px = 0; px < 8; ++px) {
            accA[px] = fmaf(wa0, lo[px], fmaf(wa1, lo[px+1], fmaf(wa2, lo[px+2], accA[px])));
            accB[px] = fmaf(wb0, hi[px], fmaf(wb1, hi[px+1], fmaf(wb2, hi[px+2], accB[px])));
          }
        }
#pragma unroll
        for (int px = 0; px < 8; ++px) {
          float y = accA[px];
          float u2m = -2.f * y * fmaf(0.0356774081f, y * y, 0.7978845608f);
          float ge = y / (1.f + __expf(u2m));
          g[(r * 8 + px) * 200 + gp] = (short)f2bf(ge * accB[px]);
        }
      }
    }
    __syncthreads();
  }

  // pout GEMM (64ch x 64pos, K=192) + residual RMW
  {
    int mt0 = wid >> 2, nt = wid & 3;
    int mt1 = mt0 + 2;
    f32x4 acc0 = {0.f, 0.f, 0.f, 0.f}, acc1 = {0.f, 0.f, 0.f, 0.f};
#pragma unroll
    for (int ks = 0; ks < 6; ++ks) {
      short8 bb = *(const short8*)(g + (nt * 16 + l15) * 200 + ks * 32 + q4 * 8);
      short8 a0 = *(const short8*)(pk_pout + ((mt0 * 6 + ks) * 64 + lane) * 8);
      short8 a1 = *(const short8*)(pk_pout + ((mt1 * 6 + ks) * 64 + lane) * 8);
      acc0 = mfma16(a0, bb, acc0);
      acc1 = mfma16(a1, bb, acc1);
    }
    int pos = nt * 16 + l15;
    int gy = wy * 8 + (pos >> 3), gx = wx * 8 + (pos & 7);
#pragma unroll
    for (int r = 0; r < 2; ++r) {
      f32x4 acc = r ? acc1 : acc0;
      int mt = r ? mt1 : mt0;
      int ob = mt * 16 + q4 * 4;
#pragma unroll
      for (int j = 0; j < 4; ++j) {
        int o = ob + j;
        size_t gp = (size_t)o * PLANE + gy * 256 + gx;
        out[gp] = acc[j] + out[gp];
      }
    }
  }
}

// ============ launch ========================================================
extern "C" void kernel_launch(void* const* d_in, const int* in_sizes, int n_in,
                              void* d_out, int out_size, void* d_ws, size_t ws_size,
                              hipStream_t stream) {
  const float* x      = (const float*)d_in[0];
  const float* ln1_w  = (const float*)d_in[1];
  const float* ln1_b  = (const float*)d_in[2];
  const float* qkv_w  = (const float*)d_in[3];
  const float* qkv_dw = (const float*)d_in[4];
  const float* temp   = (const float*)d_in[5];
  const float* proj_w = (const float*)d_in[6];
  const float* proj_b = (const float*)d_in[7];
  const float* ln2_w  = (const float*)d_in[8];
  const float* ln2_b  = (const float*)d_in[9];
  const float* pin_w  = (const float*)d_in[10];
  const float* dw_w   = (const float*)d_in[11];
  const float* pout_w = (const float*)d_in[12];
  float* out = (float*)d_out;

  // scratch: shared y-map region (46.2 MB) + packed weights (~100 KB)
  unsigned short* ybuf = (unsigned short*)d_ws;            // y1 [65536][192] / y2 [65536][352]
  short* pq = (short*)((char*)d_ws + 50331648);            // 48 MB offset
  short* pp = pq + 12288;
  short* pi = pp + 4096;
  short* po = pi + 22528;

  prepack_kernel<<<dim3(88), dim3(256), 0, stream>>>(qkv_w, proj_w, pin_w, pout_w, pq, pp, pi, po);

  for (int q = 0; q < 4; ++q) {
    size_t qoff = (size_t)q * 64 * PLANE;
    gemm_qkv<<<dim3(1024), dim3(256), 0, stream>>>(x + qoff, ln1_w, ln1_b, pq, ybuf);
    attn2_kernel<<<dim3(1024), dim3(512), 0, stream>>>(ybuf, x + qoff, qkv_dw, temp, proj_b, pp, out + qoff);
    gemm_pin<<<dim3(1024), dim3(256), 0, stream>>>(out + qoff, ln2_w, ln2_b, pi, ybuf);
    ffn2_kernel<<<dim3(1024), dim3(512), 0, stream>>>(ybuf, dw_w, po, out + qoff);
  }
}

// Round 9
// 410.139 us; speedup vs baseline: 1.4591x; 1.4591x over previous
//
#include <hip/hip_runtime.h>
#include <hip/hip_fp16.h>
#include <math.h>

typedef __attribute__((ext_vector_type(8))) short short8;
typedef __attribute__((ext_vector_type(4))) float f32x4;

#define HID 170
#define PLANE 65536

__device__ __forceinline__ unsigned short f2bf(float f) {
  unsigned u = __float_as_uint(f);
  u += 0x7FFFu + ((u >> 16) & 1u);
  return (unsigned short)(u >> 16);
}
__device__ __forceinline__ float bf2f(unsigned short h) {
  return __uint_as_float(((unsigned)h) << 16);
}
__device__ __forceinline__ unsigned pack2bf(float a, float b) {
  return (unsigned)f2bf(a) | ((unsigned)f2bf(b) << 16);
}
__device__ __forceinline__ f32x4 mfma16(short8 a, short8 b, f32x4 c) {
  return __builtin_amdgcn_mfma_f32_16x16x32_bf16(a, b, c, 0, 0, 0);
}

// ======================= prepack (weights -> bf16 fragment order) ==========
__global__ void prepack_kernel(const float* __restrict__ qkv_w, const float* __restrict__ proj_w,
                               const float* __restrict__ pin_w, const float* __restrict__ pout_w,
                               short* __restrict__ pq, short* __restrict__ pp,
                               short* __restrict__ pi, short* __restrict__ po) {
  int idx = blockIdx.x * 256 + threadIdx.x;
  if (idx < 12288) {  // qkv: 12 mtiles x 2 ksteps
    int j = idx & 7, ln = (idx >> 3) & 63, ks = (idx >> 9) & 1, mt = idx >> 10;
    int row = mt * 16 + (ln & 15), k = ks * 32 + (ln >> 4) * 8 + j;
    pq[idx] = (short)f2bf(qkv_w[row * 64 + k]);
  }
  if (idx < 4096) {   // proj: 4 x 2
    int j = idx & 7, ln = (idx >> 3) & 63, ks = (idx >> 9) & 1, mt = idx >> 10;
    int row = mt * 16 + (ln & 15), k = ks * 32 + (ln >> 4) * 8 + j;
    pp[idx] = (short)f2bf(proj_w[row * 64 + k]);
  }
  if (idx < 22528) {  // pin: 22 mt x 2 ks, chunk-local PAIR-INTERLEAVED rows
    int j = idx & 7, ln = (idx >> 3) & 63, ks = (idx >> 9) & 1, mt = idx >> 10;
    int r = mt * 16 + (ln & 15);        // 0..351
    int k = ks * 32 + (ln >> 4) * 8 + j;
    int c = r >> 7; if (c > 2) c = 2;   // chunk 0,1: 128 rows; chunk 2: 96
    int rl = r - c * 128;
    int i = c * 64 + (rl >> 1), half = rl & 1;
    float v = 0.f;
    if (i < HID) v = pin_w[(half ? HID + i : i) * 64 + k];
    pi[idx] = (short)f2bf(v);
  }
  if (idx < 12288) {  // pout: 4 mt x 6 ks (K padded 170->192)
    int j = idx & 7, ln = (idx >> 3) & 63, ks = (idx >> 9) % 6, mt = idx / 3072;
    int o = mt * 16 + (ln & 15), k = ks * 32 + (ln >> 4) * 8 + j;
    float v = (k < 170) ? pout_w[o * 170 + k] : 0.f;
    po[idx] = (short)f2bf(v);
  }
}

// ======================= layernorm (NCHW f32 -> NHWC bf16) =================
__global__ __launch_bounds__(256) void ln_kernel(
    const float* __restrict__ src, const float* __restrict__ w,
    const float* __restrict__ bia, unsigned short* __restrict__ dst) {
  __shared__ float xT[64 * 65];
  const int t = threadIdx.x;
  const int g = blockIdx.x << 6;
  const int bi = g >> 16;
  const int hw = g & 65535;
  {
    int c = t >> 2, q = t & 3;
    const float* sp = src + ((size_t)(bi * 64 + c) << 16) + hw + q * 16;
    float4 v0 = *(const float4*)(sp);
    float4 v1 = *(const float4*)(sp + 4);
    float4 v2 = *(const float4*)(sp + 8);
    float4 v3 = *(const float4*)(sp + 12);
    float* row = xT + c * 65 + q * 16;
    row[0]=v0.x; row[1]=v0.y; row[2]=v0.z; row[3]=v0.w;
    row[4]=v1.x; row[5]=v1.y; row[6]=v1.z; row[7]=v1.w;
    row[8]=v2.x; row[9]=v2.y; row[10]=v2.z; row[11]=v2.w;
    row[12]=v3.x; row[13]=v3.y; row[14]=v3.z; row[15]=v3.w;
  }
  __syncthreads();
  const int p = t >> 2, q = t & 3;
  float s = 0.f, s2 = 0.f;
  float vv[16];
#pragma unroll
  for (int i = 0; i < 16; ++i) {
    float v = xT[(q * 16 + i) * 65 + p];
    vv[i] = v; s += v; s2 += v * v;
  }
  s += __shfl_xor(s, 1); s2 += __shfl_xor(s2, 1);
  s += __shfl_xor(s, 2); s2 += __shfl_xor(s2, 2);
  float mu = s * (1.f / 64.f);
  float var = s2 * (1.f / 64.f) - mu * mu;
  float rstd = rsqrtf(var + 1e-5f);
  short8 o0, o1;
#pragma unroll
  for (int i = 0; i < 8; ++i) {
    o0[i] = (short)f2bf((vv[i] - mu) * rstd * w[q * 16 + i] + bia[q * 16 + i]);
    o1[i] = (short)f2bf((vv[8 + i] - mu) * rstd * w[q * 16 + 8 + i] + bia[q * 16 + 8 + i]);
  }
  unsigned short* dp = dst + (size_t)(g + p) * 64 + q * 16;
  *(short8*)dp = o0;
  *(short8*)(dp + 8) = o1;
}

// ======================= attn kernel ========================================
#define A_QK    0        // 128 x 72 sh = 18432
#define A_VT    18432    // 64 x 72 sh = 9216
#define A_XN    27648    // 112 x 64 sh = 14336 (swizzled [pos][chan])
#define A_QKVT  41984    // 48 pairs x 102 half2 = 19584 (ends 61568)
#define A_SCL   41984    // 128 f32 (overlays dead QKVT)
#define A_PP    42496    // 64 x 33 f32 = 8448
#define A_PB    50944    // 64 x 40 sh = 5120
#define A_OW    56064    // 64 x 72 sh = 9216
#define A_TOT   65280

__global__ __launch_bounds__(512) void attn_kernel(
    const unsigned short* __restrict__ xn1, const float* __restrict__ x,
    const float* __restrict__ qkv_dw, const float* __restrict__ temp,
    const float* __restrict__ proj_b,
    const short* __restrict__ pk_qkv, const short* __restrict__ pk_proj,
    float* __restrict__ x1out) {
  __shared__ __align__(16) char smem[A_TOT];
  short* qk      = (short*)(smem + A_QK);
  short* vt      = (short*)(smem + A_VT);
  short* xn      = (short*)(smem + A_XN);
  __half2* qkvt  = (__half2*)(smem + A_QKVT);
  float* scl     = (float*)(smem + A_SCL);
  float* pP      = (float*)(smem + A_PP);
  short* pB      = (short*)(smem + A_PB);
  short* ow      = (short*)(smem + A_OW);

  const int tid = threadIdx.x;
  const int lane = tid & 63;
  const int wid = tid >> 6;
  const int l15 = lane & 15, q4 = lane >> 4;
  const int blk = blockIdx.x;
  const int b = blk >> 10, wy = (blk >> 5) & 31, wx = blk & 31;
  const int gy0 = wy * 8 - 1, gx0 = wx * 8 - 1;
  const size_t nb = (size_t)b << 16;

  // P1: halo load (NHWC bf16) -> swizzled LDS; rows 100..111 zero
  for (int u = tid; u < 896; u += 512) {
    int p = u >> 3, q = u & 7;
    short8 v = {0, 0, 0, 0, 0, 0, 0, 0};
    if (p < 100) {
      int py = p / 10, px = p - py * 10;
      int gy = gy0 + py, gx = gx0 + px;
      if ((unsigned)gy < 256u && (unsigned)gx < 256u)
        v = *(const short8*)(xn1 + ((nb + gy * 256 + gx) << 6) + q * 8);
    }
    *(short8*)(xn + p * 64 + ((q ^ (p & 7)) << 3)) = v;
  }
  __syncthreads();

  // P2/P3: qkv GEMM -> half2-packed qkvt, then pk_fma dwconv; 2 chunks
  for (int cc = 0; cc < 2; ++cc) {
    for (int f = wid; f < 42; f += 8) {   // 6 mt x 7 nt
      int mt = f / 7, nt = f - mt * 7;
      int gmt = cc * 6 + mt;
      f32x4 acc = {0.f, 0.f, 0.f, 0.f};
#pragma unroll
      for (int ks = 0; ks < 2; ++ks) {
        short8 a = *(const short8*)(pk_qkv + ((gmt * 2 + ks) * 64 + lane) * 8);
        int pos0 = nt * 16 + l15;
        short8 bb = *(const short8*)(xn + pos0 * 64 + (((ks * 4 + q4) ^ (pos0 & 7)) << 3));
        acc = mfma16(a, bb, acc);
      }
      int pos = nt * 16 + l15;
      if (pos < 100) {
        int pr = mt * 8 + q4 * 2;
        qkvt[pr * 102 + pos]       = __floats2half2_rn(acc[0], acc[1]);
        qkvt[(pr + 1) * 102 + pos] = __floats2half2_rn(acc[2], acc[3]);
      }
    }
    __syncthreads();
    // dwconv: 48 pairs x 8 rows, packed fp16 math
    if (tid < 384) {
      int p = tid >> 3, r = tid & 7;
      int gp = cc * 48 + p;              // global pair: channels 2gp, 2gp+1
      const float* w0 = qkv_dw + gp * 18;
      const float* w1 = w0 + 9;
      __half2 w2[9];
#pragma unroll
      for (int t9 = 0; t9 < 9; ++t9) w2[t9] = __floats2half2_rn(w0[t9], w1[t9]);
      const __half2* src = qkvt + p * 102;
      __half2 a2[8];
      const __half2 z2 = __float2half2_rn(0.f);
#pragma unroll
      for (int j = 0; j < 8; ++j) a2[j] = z2;
#pragma unroll
      for (int t = 0; t < 3; ++t) {
        const __half2* rp = src + (r + t) * 10;
        uint2 u0 = *(const uint2*)(rp);
        uint2 u1 = *(const uint2*)(rp + 2);
        uint2 u2 = *(const uint2*)(rp + 4);
        uint2 u3 = *(const uint2*)(rp + 6);
        uint2 u4 = *(const uint2*)(rp + 8);
        __half2 v[10];
        v[0] = *(__half2*)&u0.x; v[1] = *(__half2*)&u0.y;
        v[2] = *(__half2*)&u1.x; v[3] = *(__half2*)&u1.y;
        v[4] = *(__half2*)&u2.x; v[5] = *(__half2*)&u2.y;
        v[6] = *(__half2*)&u3.x; v[7] = *(__half2*)&u3.y;
        v[8] = *(__half2*)&u4.x; v[9] = *(__half2*)&u4.y;
        __half2 wA = w2[t * 3], wB = w2[t * 3 + 1], wC = w2[t * 3 + 2];
#pragma unroll
        for (int px = 0; px < 8; ++px)
          a2[px] = __hfma2(wA, v[px], __hfma2(wB, v[px + 1], __hfma2(wC, v[px + 2], a2[px])));
      }
      if (gp < 64) {   // q/k channels: [chan][pos] rows, contiguous b128 stores
        short8 sa, sb;
#pragma unroll
        for (int j = 0; j < 8; ++j) {
          sa[j] = (short)f2bf(__low2float(a2[j]));
          sb[j] = (short)f2bf(__high2float(a2[j]));
        }
        *(short8*)(qk + (2 * gp) * 72 + r * 8) = sa;
        *(short8*)(qk + (2 * gp + 1) * 72 + r * 8) = sb;
      } else {         // v channels: [pos][vch] dword stores
        int vb = (gp - 64) * 2;
#pragma unroll
        for (int px = 0; px < 8; ++px)
          *(unsigned*)(vt + (r * 8 + px) * 72 + vb) =
              pack2bf(__low2float(a2[px]), __high2float(a2[px]));
      }
    }
    __syncthreads();
  }

  // P4: inverse L2 norms (128 rows x 4 lanes)
  {
    int row = tid >> 2, qq = tid & 3;
    const short* r = qk + row * 72 + qq * 16;
    short8 v0 = *(const short8*)(r);
    short8 v1 = *(const short8*)(r + 8);
    float s = 0.f;
#pragma unroll
    for (int j = 0; j < 8; ++j) {
      float f0 = bf2f((unsigned short)v0[j]); s = fmaf(f0, f0, s);
      float f1 = bf2f((unsigned short)v1[j]); s = fmaf(f1, f1, s);
    }
    s += __shfl_xor(s, 1);
    s += __shfl_xor(s, 2);
    if (qq == 0) scl[row] = 1.f / fmaxf(sqrtf(s), 1e-12f);
  }
  __syncthreads();

  // P5: QK^T logits (one 16x16 frag per wave)
  {
    int h = wid >> 2, mt = (wid >> 1) & 1, nt = wid & 1;
    int arow = h * 32 + mt * 16;
    int brow = 64 + h * 32 + nt * 16;
    f32x4 acc = {0.f, 0.f, 0.f, 0.f};
#pragma unroll
    for (int ks = 0; ks < 2; ++ks) {
      short8 a = *(const short8*)(qk + (arow + l15) * 72 + ks * 32 + q4 * 8);
      short8 bb = *(const short8*)(qk + (brow + l15) * 72 + ks * 32 + q4 * 8);
      acc = mfma16(a, bb, acc);
    }
    float tf = temp[h];
    int e = nt * 16 + l15;
    float se = scl[64 + h * 32 + e] * tf;
    int cqb = h * 32 + mt * 16 + q4 * 4;
#pragma unroll
    for (int j = 0; j < 4; ++j)
      pP[(cqb + j) * 33 + e] = acc[j] * scl[cqb + j] * se;
  }
  __syncthreads();

  // P6: softmax (64 rows x 8 lanes)
  {
    int row = tid >> 3, l = tid & 7;
    const float* rp = pP + row * 33 + l * 4;
    float e0 = rp[0], e1 = rp[1], e2 = rp[2], e3 = rp[3];
    float m = fmaxf(fmaxf(e0, e1), fmaxf(e2, e3));
    m = fmaxf(m, __shfl_xor(m, 1));
    m = fmaxf(m, __shfl_xor(m, 2));
    m = fmaxf(m, __shfl_xor(m, 4));
    float x0 = __expf(e0 - m), x1v = __expf(e1 - m);
    float x2 = __expf(e2 - m), x3 = __expf(e3 - m);
    float s = x0 + x1v + x2 + x3;
    s += __shfl_xor(s, 1);
    s += __shfl_xor(s, 2);
    s += __shfl_xor(s, 4);
    float inv = 1.f / s;
    unsigned* dp = (unsigned*)(pB + row * 40 + l * 4);
    dp[0] = pack2bf(x0 * inv, x1v * inv);
    dp[1] = pack2bf(x2 * inv, x3 * inv);
  }
  __syncthreads();

  // P7: PV (16 frags, 2 per wave)
#pragma unroll
  for (int r = 0; r < 2; ++r) {
    int f = wid + r * 8;
    int h = f >> 3, mt = (f >> 2) & 1, nt = f & 3;
    short8 a = *(const short8*)(pB + (h * 32 + mt * 16 + l15) * 40 + q4 * 8);
    short8 bb = *(const short8*)(vt + (nt * 16 + l15) * 72 + h * 32 + q4 * 8);
    f32x4 acc = {0.f, 0.f, 0.f, 0.f};
    acc = mfma16(a, bb, acc);
    int d = nt * 16 + l15;
    int chb = h * 32 + mt * 16 + q4 * 4;
    unsigned* dp = (unsigned*)(ow + d * 72 + chb);
    dp[0] = pack2bf(acc[0], acc[1]);
    dp[1] = pack2bf(acc[2], acc[3]);
  }
  __syncthreads();

  // P8: proj + bias + residual(x) -> x1 (fp32, d_out)
#pragma unroll
  for (int r = 0; r < 2; ++r) {
    int f = wid + r * 8;
    int mt = f >> 2, nt = f & 3;
    f32x4 acc = {0.f, 0.f, 0.f, 0.f};
#pragma unroll
    for (int ks = 0; ks < 2; ++ks) {
      short8 a = *(const short8*)(pk_proj + ((mt * 2 + ks) * 64 + lane) * 8);
      short8 bb = *(const short8*)(ow + (nt * 16 + l15) * 72 + ks * 32 + q4 * 8);
      acc = mfma16(a, bb, acc);
    }
    int pos = nt * 16 + l15;
    int gy = wy * 8 + (pos >> 3), gx = wx * 8 + (pos & 7);
    int ob = mt * 16 + q4 * 4;
#pragma unroll
    for (int j = 0; j < 4; ++j) {
      int o = ob + j;
      size_t gp = (size_t)(b * 64 + o) * PLANE + gy * 256 + gx;
      x1out[gp] = acc[j] + proj_b[o] + x[gp];
    }
  }
}

// ======================= ffn kernel =========================================
#define F_XN  0       // 112x64 sh = 14336
#define F_Y12 14336   // 64 pairs x 102 half2 = 26112 (ends 40448)
#define F_G   40448   // 64 x 72 sh = 9216
#define F_TOT 49664   // -> 3 blocks/CU

__global__ __launch_bounds__(512) void ffn_kernel(
    const unsigned short* __restrict__ xn2,
    const float* __restrict__ dw_w,
    const short* __restrict__ pk_pin, const short* __restrict__ pk_pout,
    float* __restrict__ out) {
  __shared__ __align__(16) char smem[F_TOT];
  short* xn     = (short*)(smem + F_XN);
  __half2* y12  = (__half2*)(smem + F_Y12);
  short* g      = (short*)(smem + F_G);

  const int tid = threadIdx.x;
  const int lane = tid & 63;
  const int wid = tid >> 6;
  const int l15 = lane & 15, q4 = lane >> 4;
  const int blk = blockIdx.x;
  const int b = blk >> 10, wy = (blk >> 5) & 31, wx = blk & 31;
  const int gy0 = wy * 8 - 1, gx0 = wx * 8 - 1;
  const size_t nb = (size_t)b << 16;

  // P1: halo load
  for (int u = tid; u < 896; u += 512) {
    int p = u >> 3, q = u & 7;
    short8 v = {0, 0, 0, 0, 0, 0, 0, 0};
    if (p < 100) {
      int py = p / 10, px = p - py * 10;
      int gy = gy0 + py, gx = gx0 + px;
      if ((unsigned)gy < 256u && (unsigned)gx < 256u)
        v = *(const short8*)(xn2 + ((nb + gy * 256 + gx) << 6) + q * 8);
    }
    *(short8*)(xn + p * 64 + ((q ^ (p & 7)) << 3)) = v;
  }
  __syncthreads();

  f32x4 acc0 = {0.f, 0.f, 0.f, 0.f}, acc1 = {0.f, 0.f, 0.f, 0.f};

  for (int cc2 = 0; cc2 < 3; ++cc2) {
    const int MT = (cc2 < 2) ? 8 : 6;
    const int mbase = cc2 * 8;
    // pin GEMM chunk -> y12 half2 pairs (y in lo, z in hi)
    for (int f = wid; f < MT * 7; f += 8) {
      int lm = f / 7, nt = f - lm * 7;
      int gmt = mbase + lm;
      f32x4 acc = {0.f, 0.f, 0.f, 0.f};
#pragma unroll
      for (int ks = 0; ks < 2; ++ks) {
        short8 a = *(const short8*)(pk_pin + ((gmt * 2 + ks) * 64 + lane) * 8);
        int pos0 = nt * 16 + l15;
        short8 bb = *(const short8*)(xn + pos0 * 64 + (((ks * 4 + q4) ^ (pos0 & 7)) << 3));
        acc = mfma16(a, bb, acc);
      }
      int pos = nt * 16 + l15;
      if (pos < 100) {
        int pr = lm * 8 + q4 * 2;
        y12[pr * 102 + pos]       = __floats2half2_rn(acc[0], acc[1]);
        y12[(pr + 1) * 102 + pos] = __floats2half2_rn(acc[2], acc[3]);
      }
    }
    __syncthreads();
    // dwconv + gelu gate (packed fp16) -> g[pos][i]
    {
      int nv = (cc2 < 2) ? 64 : 42;
      int p = tid >> 3, r = tid & 7;
      if (p < nv) {
        int gi = cc2 * 64 + p;
        const float* wY = dw_w + gi * 9;
        const float* wZ = dw_w + (HID + gi) * 9;
        __half2 w2[9];
#pragma unroll
        for (int t9 = 0; t9 < 9; ++t9) w2[t9] = __floats2half2_rn(wY[t9], wZ[t9]);
        const __half2* src = y12 + p * 102;
        __half2 a2[8];
        const __half2 z2 = __float2half2_rn(0.f);
#pragma unroll
        for (int j = 0; j < 8; ++j) a2[j] = z2;
#pragma unroll
        for (int t = 0; t < 3; ++t) {
          const __half2* rp = src + (r + t) * 10;
          uint2 u0 = *(const uint2*)(rp);
          uint2 u1 = *(const uint2*)(rp + 2);
          uint2 u2 = *(const uint2*)(rp + 4);
          uint2 u3 = *(const uint2*)(rp + 6);
          uint2 u4 = *(const uint2*)(rp + 8);
          __half2 v[10];
          v[0] = *(__half2*)&u0.x; v[1] = *(__half2*)&u0.y;
          v[2] = *(__half2*)&u1.x; v[3] = *(__half2*)&u1.y;
          v[4] = *(__half2*)&u2.x; v[5] = *(__half2*)&u2.y;
          v[6] = *(__half2*)&u3.x; v[7] = *(__half2*)&u3.y;
          v[8] = *(__half2*)&u4.x; v[9] = *(__half2*)&u4.y;
          __half2 wA = w2[t * 3], wB = w2[t * 3 + 1], wC = w2[t * 3 + 2];
#pragma unroll
          for (int px = 0; px < 8; ++px)
            a2[px] = __hfma2(wA, v[px], __hfma2(wB, v[px + 1], __hfma2(wC, v[px + 2], a2[px])));
        }
#pragma unroll
        for (int px = 0; px < 8; ++px) {
          float y = __low2float(a2[px]);
          float z = __high2float(a2[px]);
          float u2m = -2.f * y * fmaf(0.0356774081f, y * y, 0.7978845608f);
          float ge = y / (1.f + __expf(u2m));
          g[(r * 8 + px) * 72 + p] = (short)f2bf(ge * z);
        }
      }
    }
    __syncthreads();
    // pout partial GEMM (accumulate across chunks in registers)
    {
      int mt0 = wid >> 2, nt = wid & 3;
      int mt1 = mt0 + 2;
#pragma unroll
      for (int ks = 0; ks < 2; ++ks) {
        int gks = cc2 * 2 + ks;
        short8 bb = *(const short8*)(g + (nt * 16 + l15) * 72 + ks * 32 + q4 * 8);
        short8 a0 = *(const short8*)(pk_pout + ((mt0 * 6 + gks) * 64 + lane) * 8);
        short8 a1 = *(const short8*)(pk_pout + ((mt1 * 6 + gks) * 64 + lane) * 8);
        acc0 = mfma16(a0, bb, acc0);
        acc1 = mfma16(a1, bb, acc1);
      }
    }
    __syncthreads();
  }

  // epilogue: in-place residual RMW on d_out
  {
    int mt0 = wid >> 2, nt = wid & 3;
    int pos = nt * 16 + l15;
    int gy = wy * 8 + (pos >> 3), gx = wx * 8 + (pos & 7);
#pragma unroll
    for (int r = 0; r < 2; ++r) {
      f32x4 acc = r ? acc1 : acc0;
      int mt = r ? (mt0 + 2) : mt0;
      int ob = mt * 16 + q4 * 4;
#pragma unroll
      for (int j = 0; j < 4; ++j) {
        int o = ob + j;
        size_t gp = (size_t)(b * 64 + o) * PLANE + gy * 256 + gx;
        out[gp] = acc[j] + out[gp];
      }
    }
  }
}

// ======================= launch =============================================
extern "C" void kernel_launch(void* const* d_in, const int* in_sizes, int n_in,
                              void* d_out, int out_size, void* d_ws, size_t ws_size,
                              hipStream_t stream) {
  const float* x      = (const float*)d_in[0];
  const float* ln1_w  = (const float*)d_in[1];
  const float* ln1_b  = (const float*)d_in[2];
  const float* qkv_w  = (const float*)d_in[3];
  const float* qkv_dw = (const float*)d_in[4];
  const float* temp   = (const float*)d_in[5];
  const float* proj_w = (const float*)d_in[6];
  const float* proj_b = (const float*)d_in[7];
  const float* ln2_w  = (const float*)d_in[8];
  const float* ln2_b  = (const float*)d_in[9];
  const float* pin_w  = (const float*)d_in[10];
  const float* dw_w   = (const float*)d_in[11];
  const float* pout_w = (const float*)d_in[12];
  float* out = (float*)d_out;

  unsigned short* xnbuf = (unsigned short*)d_ws;           // bf16 NHWC, 33.5 MB
  short* pq = (short*)((char*)d_ws + 33554432);
  short* pp = pq + 12288;
  short* pi = pp + 4096;
  short* po = pi + 22528;

  prepack_kernel<<<dim3(88), dim3(256), 0, stream>>>(qkv_w, proj_w, pin_w, pout_w, pq, pp, pi, po);
  ln_kernel<<<dim3(4096), dim3(256), 0, stream>>>(x, ln1_w, ln1_b, xnbuf);
  attn_kernel<<<dim3(4096), dim3(512), 0, stream>>>(xnbuf, x, qkv_dw, temp, proj_b, pq, pp, out);
  ln_kernel<<<dim3(4096), dim3(256), 0, stream>>>(out, ln2_w, ln2_b, xnbuf);
  ffn_kernel<<<dim3(4096), dim3(512), 0, stream>>>(xnbuf, dw_w, pi, po, out);
}